// Round 4
// baseline (1148.462 us; speedup 1.0000x reference)
//
#include <hip/hip_runtime.h>

#define EPS 1e-5f
#define NTHR 256
#define NBLK 1024
#define NSLOT 16

typedef __bf16 bf16x8 __attribute__((ext_vector_type(8)));
typedef float f32x16 __attribute__((ext_vector_type(16)));

// d_ws layout:
//   [0, N*16*2)                   bf16 copy of x, tile-major in MFMA B-frag order:
//                                 xb[(t*64 + lane)*8 .. +8) = 8 bf16 for (tile t, lane)
//   [N*16*2, +3*NSLOT*64*4)       stats slots: layer L: stats[L*NSLOT*64 + slot*64 + idx]
//                                 idx 0..31 = sum(z_L), 32..63 = sum(z_L^2)
//   [.. +8)                       grid barrier {count, generation}
//
// Layout algebra (m74/m101-verified 32x32x16 mappings):
//   C/D: col=lane&31 (data row), row p = (reg&3)+8*(reg>>2)+4h, h=lane>>5
//   A:   m=lane&31, k=8h+j ;  B: n=lane&31, k=8h+j
// Acc regs 0..7 / 8..15 feed the next layer's B-frag; next weights use columns
// permuted by phi(K)=(j&3)+8*(j>>2)+4h+16*kh (involution). BN scale a>0 folds
// into next-layer weight columns; shift e folds into the MFMA accumulator init.
//
// R4 change: R3's counters showed the fused kernel is stall-bound at 24%
// occupancy (hbm 10%, valu 15%, mfma 4%) — per-phase time scaled ~1/waves vs
// the 16-waves/CU 4-kernel version. Fix: NBLK 512->1024 (4 blocks/CU,
// __launch_bounds__(256,4); 88 VGPR <= 128 cap so co-residency for the grid
// barrier still holds) + unguarded main-loop batches (exact work split, no
// per-tile `if` -> loads issue back-to-back, clean waitcnt).

__global__ __launch_bounds__(NTHR, 4) void k_all(
    const float* __restrict__ x, __bf16* __restrict__ xb,
    const float* __restrict__ W1, const float* __restrict__ b1,
    const float* __restrict__ g1, const float* __restrict__ be1,
    const float* __restrict__ W2, const float* __restrict__ b2,
    const float* __restrict__ g2, const float* __restrict__ be2,
    const float* __restrict__ W3, const float* __restrict__ b3,
    const float* __restrict__ g3, const float* __restrict__ be3,
    const float* __restrict__ W4, const float* __restrict__ b4,
    float* __restrict__ stats, unsigned* __restrict__ bar,
    float* __restrict__ out, int N)
{
    __shared__ float s_stat[64];
    __shared__ float s_a[32];
    __shared__ float s_e[32];
    __shared__ float s_w[NTHR / 64][64];

    const int tid = threadIdx.x;
    const int lane = tid & 63;
    const int h = lane >> 5;
    const int ml = lane & 31;
    const float invN = 1.0f / (float)N;

    const int ntiles = N >> 5;
    const int nwaves = NBLK * (NTHR / 64);
    const int gwave  = blockIdx.x * (NTHR / 64) + (tid >> 6);
    const int tpw    = ntiles / nwaves;
    const int rem    = ntiles - tpw * nwaves;
    const int t0     = gwave * tpw + (gwave < rem ? gwave : rem);
    const int cnt    = tpw + (gwave < rem ? 1 : 0);
    const int tend   = t0 + cnt;

    // ---- device-scope grid barrier (sense via monotone generation) ----
    auto gbar = [&](unsigned target) {
        __syncthreads();
        if (tid == 0) {
            __threadfence();
            unsigned old = __hip_atomic_fetch_add(&bar[0], 1u, __ATOMIC_ACQ_REL, __HIP_MEMORY_SCOPE_AGENT);
            if (old == (unsigned)(NBLK - 1)) {
                __hip_atomic_store(&bar[0], 0u, __ATOMIC_RELAXED, __HIP_MEMORY_SCOPE_AGENT);
                __hip_atomic_fetch_add(&bar[1], 1u, __ATOMIC_RELEASE, __HIP_MEMORY_SCOPE_AGENT);
            } else {
                while (__hip_atomic_load(&bar[1], __ATOMIC_ACQUIRE, __HIP_MEMORY_SCOPE_AGENT) < target)
                    __builtin_amdgcn_s_sleep(2);
            }
        }
        __syncthreads();
    };

    // ---- combine stats slots for layer L, derive BN scale a / shift e ----
    auto derive = [&](int L, const float* g, const float* be, const float* b) {
        if (tid < 64) {
            float a = 0.f;
            #pragma unroll
            for (int s = 0; s < NSLOT; ++s)
                a += __hip_atomic_load(&stats[L * (NSLOT * 64) + s * 64 + tid],
                                       __ATOMIC_RELAXED, __HIP_MEMORY_SCOPE_AGENT);
            s_stat[tid] = a;
        }
        __syncthreads();
        if (tid < 32) {
            float mu = s_stat[tid] * invN;
            float v  = s_stat[32 + tid] * invN - mu * mu;
            float a  = g[tid] * rsqrtf(v + EPS);
            s_a[tid] = a;
            s_e[tid] = b[tid] - mu + be[tid] / a;
        }
        __syncthreads();
    };

    float sums[16], sqs[16];

    // ---- block-reduce per-wave stats, one atomic per feature per block ----
    auto flush_stats = [&](int L) {
        const int wid = tid >> 6;
        #pragma unroll
        for (int i = 0; i < 16; ++i) {
            float s = sums[i], q = sqs[i];
            #pragma unroll
            for (int d = 1; d <= 16; d <<= 1) {
                s += __shfl_xor(s, d);
                q += __shfl_xor(q, d);
            }
            if (ml == 0) {
                int p = (i & 3) + 8 * (i >> 2) + 4 * h;
                s_w[wid][p] = s;
                s_w[wid][32 + p] = q;
            }
        }
        __syncthreads();
        if (tid < 64) {
            float a = s_w[0][tid] + s_w[1][tid] + s_w[2][tid] + s_w[3][tid];
            atomicAdd(&stats[L * (NSLOT * 64) + (blockIdx.x & (NSLOT - 1)) * 64 + tid], a);
        }
    };

    // ---- persistent fragments ----
    bf16x8 w1f;
    {
        const float* p = W1 + ml * 16 + h * 8;
        #pragma unroll
        for (int j = 0; j < 8; ++j) w1f[j] = (__bf16)p[j];
    }
    f32x16 c1;
    #pragma unroll
    for (int i = 0; i < 16; ++i) {
        int p = (i & 3) + 8 * (i >> 2) + 4 * h;
        c1[i] = b1[p];
    }

    // ================= phase 1: stage xb, stats of z1 =================
    #pragma unroll
    for (int i = 0; i < 16; ++i) { sums[i] = 0.f; sqs[i] = 0.f; }
    {
        auto body1 = [&](int t, float4 u0, float4 u1) {
            bf16x8 xf;
            xf[0] = (__bf16)u0.x; xf[1] = (__bf16)u0.y;
            xf[2] = (__bf16)u0.z; xf[3] = (__bf16)u0.w;
            xf[4] = (__bf16)u1.x; xf[5] = (__bf16)u1.y;
            xf[6] = (__bf16)u1.z; xf[7] = (__bf16)u1.w;
            *(bf16x8*)(xb + ((size_t)t * 64 + lane) * 8) = xf;
            f32x16 a1 = __builtin_amdgcn_mfma_f32_32x32x16_bf16(w1f, xf, c1, 0, 0, 0);
            #pragma unroll
            for (int q = 0; q < 16; ++q) { sums[q] += a1[q]; sqs[q] = fmaf(a1[q], a1[q], sqs[q]); }
        };
        int i0 = 0;
        for (; i0 + 4 <= cnt; i0 += 4) {
            float4 u0[4], u1[4];
            #pragma unroll
            for (int k = 0; k < 4; ++k) {
                int row = ((t0 + i0 + k) << 5) + ml;
                const float4* xp = (const float4*)(x + (size_t)row * 16 + h * 8);
                u0[k] = xp[0]; u1[k] = xp[1];
            }
            #pragma unroll
            for (int k = 0; k < 4; ++k) body1(t0 + i0 + k, u0[k], u1[k]);
        }
        for (; i0 < cnt; ++i0) {
            int row = ((t0 + i0) << 5) + ml;
            const float4* xp = (const float4*)(x + (size_t)row * 16 + h * 8);
            body1(t0 + i0, xp[0], xp[1]);
        }
    }
    flush_stats(0);
    gbar(1);

    // ================= phase 2: stats of z2 (reverse traversal) =================
    derive(0, g1, be1, b1);
    #pragma unroll
    for (int i = 0; i < 16; ++i) {
        int p = (i & 3) + 8 * (i >> 2) + 4 * h;
        c1[i] = s_e[p];
    }
    bf16x8 w2f0, w2f1;
    #pragma unroll
    for (int kh = 0; kh < 2; ++kh)
        #pragma unroll
        for (int j = 0; j < 8; ++j) {
            int pk = (j & 3) + 8 * (j >> 2) + 4 * h + 16 * kh;
            float v = W2[ml * 32 + pk] * s_a[pk];
            if (kh == 0) w2f0[j] = (__bf16)v; else w2f1[j] = (__bf16)v;
        }
    f32x16 c2;
    #pragma unroll
    for (int i = 0; i < 16; ++i) {
        int p = (i & 3) + 8 * (i >> 2) + 4 * h;
        c2[i] = b2[p];
    }
    #pragma unroll
    for (int i = 0; i < 16; ++i) { sums[i] = 0.f; sqs[i] = 0.f; }
    {
        auto body2 = [&](bf16x8 xf) {
            f32x16 a1 = __builtin_amdgcn_mfma_f32_32x32x16_bf16(w1f, xf, c1, 0, 0, 0);
            bf16x8 qa, qb;
            #pragma unroll
            for (int j = 0; j < 8; ++j) {
                qa[j] = (__bf16)fmaxf(a1[j], 0.f);
                qb[j] = (__bf16)fmaxf(a1[8 + j], 0.f);
            }
            f32x16 a2 = __builtin_amdgcn_mfma_f32_32x32x16_bf16(w2f0, qa, c2, 0, 0, 0);
            a2 = __builtin_amdgcn_mfma_f32_32x32x16_bf16(w2f1, qb, a2, 0, 0, 0);
            #pragma unroll
            for (int q = 0; q < 16; ++q) { sums[q] += a2[q]; sqs[q] = fmaf(a2[q], a2[q], sqs[q]); }
        };
        int i0 = 0;
        for (; i0 + 4 <= cnt; i0 += 4) {
            bf16x8 xf[4];
            #pragma unroll
            for (int k = 0; k < 4; ++k) {
                int t = tend - 1 - (i0 + k);
                xf[k] = *(const bf16x8*)(xb + ((size_t)t * 64 + lane) * 8);
            }
            #pragma unroll
            for (int k = 0; k < 4; ++k) body2(xf[k]);
        }
        for (; i0 < cnt; ++i0) {
            int t = tend - 1 - i0;
            body2(*(const bf16x8*)(xb + ((size_t)t * 64 + lane) * 8));
        }
    }
    flush_stats(1);
    gbar(2);

    // ================= phase 3: stats of z3 (forward) =================
    derive(1, g2, be2, b2);
    #pragma unroll
    for (int i = 0; i < 16; ++i) {
        int p = (i & 3) + 8 * (i >> 2) + 4 * h;
        c2[i] = s_e[p];
    }
    bf16x8 w3f0, w3f1;
    #pragma unroll
    for (int kh = 0; kh < 2; ++kh)
        #pragma unroll
        for (int j = 0; j < 8; ++j) {
            int pk = (j & 3) + 8 * (j >> 2) + 4 * h + 16 * kh;
            float v = W3[ml * 32 + pk] * s_a[pk];
            if (kh == 0) w3f0[j] = (__bf16)v; else w3f1[j] = (__bf16)v;
        }
    f32x16 c3;
    #pragma unroll
    for (int i = 0; i < 16; ++i) {
        int p = (i & 3) + 8 * (i >> 2) + 4 * h;
        c3[i] = b3[p];
    }
    #pragma unroll
    for (int i = 0; i < 16; ++i) { sums[i] = 0.f; sqs[i] = 0.f; }
    {
        auto body3 = [&](bf16x8 xf) {
            f32x16 a1 = __builtin_amdgcn_mfma_f32_32x32x16_bf16(w1f, xf, c1, 0, 0, 0);
            bf16x8 qa, qb;
            #pragma unroll
            for (int j = 0; j < 8; ++j) {
                qa[j] = (__bf16)fmaxf(a1[j], 0.f);
                qb[j] = (__bf16)fmaxf(a1[8 + j], 0.f);
            }
            f32x16 a2 = __builtin_amdgcn_mfma_f32_32x32x16_bf16(w2f0, qa, c2, 0, 0, 0);
            a2 = __builtin_amdgcn_mfma_f32_32x32x16_bf16(w2f1, qb, a2, 0, 0, 0);
            bf16x8 pa, pb;
            #pragma unroll
            for (int j = 0; j < 8; ++j) {
                pa[j] = (__bf16)fmaxf(a2[j], 0.f);
                pb[j] = (__bf16)fmaxf(a2[8 + j], 0.f);
            }
            f32x16 a3 = __builtin_amdgcn_mfma_f32_32x32x16_bf16(w3f0, pa, c3, 0, 0, 0);
            a3 = __builtin_amdgcn_mfma_f32_32x32x16_bf16(w3f1, pb, a3, 0, 0, 0);
            #pragma unroll
            for (int q = 0; q < 16; ++q) { sums[q] += a3[q]; sqs[q] = fmaf(a3[q], a3[q], sqs[q]); }
        };
        int i0 = 0;
        for (; i0 + 4 <= cnt; i0 += 4) {
            bf16x8 xf[4];
            #pragma unroll
            for (int k = 0; k < 4; ++k) {
                int t = t0 + i0 + k;
                xf[k] = *(const bf16x8*)(xb + ((size_t)t * 64 + lane) * 8);
            }
            #pragma unroll
            for (int k = 0; k < 4; ++k) body3(xf[k]);
        }
        for (; i0 < cnt; ++i0) {
            int t = t0 + i0;
            body3(*(const bf16x8*)(xb + ((size_t)t * 64 + lane) * 8));
        }
    }
    flush_stats(2);
    gbar(3);

    // ================= phase 4: output (reverse traversal) =================
    derive(2, g3, be3, b3);
    #pragma unroll
    for (int i = 0; i < 16; ++i) {
        int p = (i & 3) + 8 * (i >> 2) + 4 * h;
        c3[i] = s_e[p];
    }
    float w4c[16];
    #pragma unroll
    for (int i = 0; i < 16; ++i) {
        int p = (i & 3) + 8 * (i >> 2) + 4 * h;
        w4c[i] = W4[p] * s_a[p];
    }
    const float b4v = b4[0];
    {
        auto body4 = [&](int t, bf16x8 xf) {
            f32x16 a1 = __builtin_amdgcn_mfma_f32_32x32x16_bf16(w1f, xf, c1, 0, 0, 0);
            bf16x8 qa, qb;
            #pragma unroll
            for (int j = 0; j < 8; ++j) {
                qa[j] = (__bf16)fmaxf(a1[j], 0.f);
                qb[j] = (__bf16)fmaxf(a1[8 + j], 0.f);
            }
            f32x16 a2 = __builtin_amdgcn_mfma_f32_32x32x16_bf16(w2f0, qa, c2, 0, 0, 0);
            a2 = __builtin_amdgcn_mfma_f32_32x32x16_bf16(w2f1, qb, a2, 0, 0, 0);
            bf16x8 pa, pb;
            #pragma unroll
            for (int j = 0; j < 8; ++j) {
                pa[j] = (__bf16)fmaxf(a2[j], 0.f);
                pb[j] = (__bf16)fmaxf(a2[8 + j], 0.f);
            }
            f32x16 a3 = __builtin_amdgcn_mfma_f32_32x32x16_bf16(w3f0, pa, c3, 0, 0, 0);
            a3 = __builtin_amdgcn_mfma_f32_32x32x16_bf16(w3f1, pb, a3, 0, 0, 0);
            float o = 0.f;
            #pragma unroll
            for (int q = 0; q < 16; ++q) o = fmaf(w4c[q], fmaxf(a3[q], 0.f), o);
            o += __shfl_xor(o, 32);
            if (h == 0) out[(t << 5) + ml] = o + b4v;
        };
        int i0 = 0;
        for (; i0 + 4 <= cnt; i0 += 4) {
            bf16x8 xf[4];
            #pragma unroll
            for (int k = 0; k < 4; ++k) {
                int t = tend - 1 - (i0 + k);
                xf[k] = *(const bf16x8*)(xb + ((size_t)t * 64 + lane) * 8);
            }
            #pragma unroll
            for (int k = 0; k < 4; ++k) body4(tend - 1 - (i0 + k), xf[k]);
        }
        for (; i0 < cnt; ++i0) {
            int t = tend - 1 - i0;
            body4(t, *(const bf16x8*)(xb + ((size_t)t * 64 + lane) * 8));
        }
    }
}

extern "C" void kernel_launch(void* const* d_in, const int* in_sizes, int n_in,
                              void* d_out, int out_size, void* d_ws, size_t ws_size,
                              hipStream_t stream) {
    const float* x   = (const float*)d_in[0];
    const float* W1  = (const float*)d_in[1];
    const float* b1  = (const float*)d_in[2];
    const float* g1  = (const float*)d_in[3];
    const float* be1 = (const float*)d_in[4];
    const float* W2  = (const float*)d_in[5];
    const float* b2  = (const float*)d_in[6];
    const float* g2  = (const float*)d_in[7];
    const float* be2 = (const float*)d_in[8];
    const float* W3  = (const float*)d_in[9];
    const float* b3  = (const float*)d_in[10];
    const float* g3  = (const float*)d_in[11];
    const float* be3 = (const float*)d_in[12];
    const float* W4  = (const float*)d_in[13];
    const float* b4  = (const float*)d_in[14];
    float* out = (float*)d_out;
    int N = in_sizes[0] / 16;

    __bf16* xb    = (__bf16*)d_ws;
    float* stats  = (float*)((char*)d_ws + (size_t)N * 16 * 2);
    unsigned* bar = (unsigned*)((char*)stats + 3 * NSLOT * 64 * sizeof(float));

    // zero stats slots + barrier {count, gen}
    hipMemsetAsync(stats, 0, 3 * NSLOT * 64 * sizeof(float) + 64, stream);

    k_all<<<NBLK, NTHR, 0, stream>>>(x, xb, W1, b1, g1, be1, W2, b2, g2, be2,
                                     W3, b3, g3, be3, W4, b4, stats, bar, out, N);
}

// Round 5
// 360.410 us; speedup vs baseline: 3.1865x; 3.1865x over previous
//
#include <hip/hip_runtime.h>

#define EPS 1e-5f
#define NTHR 256
#define NBLK 2048
#define NSLOT 16

typedef __bf16 bf16x8 __attribute__((ext_vector_type(8)));
typedef float f32x16 __attribute__((ext_vector_type(16)));

// d_ws layout:
//   [0, 3*NSLOT*64*4)  stats slots: layer L: stats[L*NSLOT*64 + slot*64 + idx]
//                      idx 0..31 = sum(z_L), 32..63 = sum(z_L^2)
//
// Layout algebra (m74/m101-verified 32x32x16 mappings):
//   C/D: col=lane&31 (data row), row p = (reg&3)+8*(reg>>2)+4h, h=lane>>5
//   A:   m=lane&31, k=8h+j ;  B: n=lane&31, k=8h+j
// Acc regs 0..7 / 8..15 feed the next layer's B-frag; next weights use columns
// permuted by phi(K)=(j&3)+8*(j>>2)+4h+16*kh (involution). BN scale a>0 folds
// into next-layer weight columns; shift e folds into the MFMA accumulator init.
//
// R5: back to separate kernels (persistent+gbar caps waves via co-residency;
// R4's launch_bounds(256,4) additionally caused massive scratch spills —
// FETCH 146->608MB, WRITE 74->310MB). Changes vs the proven R2 code ONLY:
//   1. no xb staging: x (128MB fp32) is L3-resident (L3=256MB) after D1;
//      D2-D4 re-read x from L3 + convert inline. Saves 64MB HBM write,
//      bit-identical results (same fp32->bf16 rounding each pass).
//   2. NBLK 2048: no co-residency constraint; HW packs ~20 waves/CU at
//      ~90 VGPR and block turnover adds latency hiding.
//   3. plain __launch_bounds__(256): never cap VGPR below need (R4 lesson).

template<int DEPTH>
__global__ __launch_bounds__(NTHR) void k_fwd(
    const float* __restrict__ x,
    const float* __restrict__ W1, const float* __restrict__ b1,
    const float* __restrict__ g1, const float* __restrict__ be1,
    const float* __restrict__ W2, const float* __restrict__ b2,
    const float* __restrict__ g2, const float* __restrict__ be2,
    const float* __restrict__ W3, const float* __restrict__ b3,
    const float* __restrict__ g3, const float* __restrict__ be3,
    const float* __restrict__ W4, const float* __restrict__ b4,
    float* __restrict__ stats, float* __restrict__ out, int N)
{
    constexpr bool STATS = (DEPTH < 4);
    __shared__ float s_stat[3][64];
    __shared__ float s_a[3][32];
    __shared__ float s_e[3][32];
    __shared__ float s_w[NTHR / 64][64];

    const int tid = threadIdx.x;
    const float invN = 1.0f / (float)N;

    // Phase A: combine slot partials for layers whose stats are known
    if (tid < 64) {
        for (int L = 0; L < DEPTH - 1; ++L) {
            float a = 0.f;
            #pragma unroll
            for (int s = 0; s < NSLOT; ++s) a += stats[L * (NSLOT * 64) + s * 64 + tid];
            s_stat[L][tid] = a;
        }
    }
    __syncthreads();
    // Phase B: derive BN scale a and additive fold e per feature
    if (tid < 32) {
        const float* gs[3]  = {g1, g2, g3};
        const float* bes[3] = {be1, be2, be3};
        const float* bs[3]  = {b1, b2, b3};
        for (int L = 0; L < DEPTH - 1; ++L) {
            float mu = s_stat[L][tid] * invN;
            float v  = s_stat[L][32 + tid] * invN - mu * mu;
            float a  = gs[L][tid] * rsqrtf(v + EPS);
            s_a[L][tid] = a;
            s_e[L][tid] = bs[L][tid] - mu + bes[L][tid] / a;
        }
    }
    __syncthreads();

    // Phase C: per-thread fragments and constants
    const int lane = tid & 63;
    const int h = lane >> 5;
    const int ml = lane & 31;

    bf16x8 w1f;
    {
        const float* p = W1 + ml * 16 + h * 8;
        #pragma unroll
        for (int j = 0; j < 8; ++j) w1f[j] = (__bf16)p[j];
    }
    bf16x8 w2f0 = {}, w2f1 = {}, w3f0 = {}, w3f1 = {};
    if (DEPTH >= 2) {
        #pragma unroll
        for (int kh = 0; kh < 2; ++kh)
            #pragma unroll
            for (int j = 0; j < 8; ++j) {
                int pk = (j & 3) + 8 * (j >> 2) + 4 * h + 16 * kh;
                float v = W2[ml * 32 + pk] * s_a[0][pk];
                if (kh == 0) w2f0[j] = (__bf16)v; else w2f1[j] = (__bf16)v;
            }
    }
    if (DEPTH >= 3) {
        #pragma unroll
        for (int kh = 0; kh < 2; ++kh)
            #pragma unroll
            for (int j = 0; j < 8; ++j) {
                int pk = (j & 3) + 8 * (j >> 2) + 4 * h + 16 * kh;
                float v = W3[ml * 32 + pk] * s_a[1][pk];
                if (kh == 0) w3f0[j] = (__bf16)v; else w3f1[j] = (__bf16)v;
            }
    }

    f32x16 c1, c2 = {}, c3 = {};
    float w4c[16];
    #pragma unroll
    for (int i = 0; i < 16; ++i) {
        int p = (i & 3) + 8 * (i >> 2) + 4 * h;
        c1[i] = (DEPTH == 1) ? b1[p] : s_e[0][p];
        if (DEPTH >= 2) c2[i] = (DEPTH == 2) ? b2[p] : s_e[1][p];
        if (DEPTH >= 3) c3[i] = (DEPTH == 3) ? b3[p] : s_e[2][p];
        if (DEPTH == 4) w4c[i] = W4[p] * s_a[2][p]; else w4c[i] = 0.f;
    }
    const float b4v = (DEPTH == 4) ? b4[0] : 0.f;

    const int ntiles = N >> 5;
    const int nwaves = gridDim.x * (NTHR / 64);
    const int gwave  = blockIdx.x * (NTHR / 64) + (tid >> 6);

    float sums[16], sqs[16];
    #pragma unroll
    for (int i = 0; i < 16; ++i) { sums[i] = 0.f; sqs[i] = 0.f; }

    auto tile = [&](int t, bf16x8 xf) {
        f32x16 a1 = __builtin_amdgcn_mfma_f32_32x32x16_bf16(w1f, xf, c1, 0, 0, 0);
        if (DEPTH == 1) {
            #pragma unroll
            for (int i = 0; i < 16; ++i) { sums[i] += a1[i]; sqs[i] = fmaf(a1[i], a1[i], sqs[i]); }
            return;
        }
        bf16x8 qa, qb;
        #pragma unroll
        for (int j = 0; j < 8; ++j) {
            qa[j] = (__bf16)fmaxf(a1[j], 0.f);
            qb[j] = (__bf16)fmaxf(a1[8 + j], 0.f);
        }
        f32x16 a2 = __builtin_amdgcn_mfma_f32_32x32x16_bf16(w2f0, qa, c2, 0, 0, 0);
        a2 = __builtin_amdgcn_mfma_f32_32x32x16_bf16(w2f1, qb, a2, 0, 0, 0);
        if (DEPTH == 2) {
            #pragma unroll
            for (int i = 0; i < 16; ++i) { sums[i] += a2[i]; sqs[i] = fmaf(a2[i], a2[i], sqs[i]); }
            return;
        }
        bf16x8 pa, pb;
        #pragma unroll
        for (int j = 0; j < 8; ++j) {
            pa[j] = (__bf16)fmaxf(a2[j], 0.f);
            pb[j] = (__bf16)fmaxf(a2[8 + j], 0.f);
        }
        f32x16 a3 = __builtin_amdgcn_mfma_f32_32x32x16_bf16(w3f0, pa, c3, 0, 0, 0);
        a3 = __builtin_amdgcn_mfma_f32_32x32x16_bf16(w3f1, pb, a3, 0, 0, 0);
        if (DEPTH == 3) {
            #pragma unroll
            for (int i = 0; i < 16; ++i) { sums[i] += a3[i]; sqs[i] = fmaf(a3[i], a3[i], sqs[i]); }
            return;
        }
        float o = 0.f;
        #pragma unroll
        for (int i = 0; i < 16; ++i) o = fmaf(w4c[i], fmaxf(a3[i], 0.f), o);
        o += __shfl_xor(o, 32);
        if (h == 0) out[(t << 5) + ml] = o + b4v;
    };

    // 4-deep fp32 load batching (all depths read x directly; L3-resident after D1)
    for (int t0 = gwave; t0 < ntiles; t0 += 4 * nwaves) {
        float4 u0[4], u1[4];
        #pragma unroll
        for (int k = 0; k < 4; ++k) {
            int t = t0 + k * nwaves;
            if (t < ntiles) {
                int row = (t << 5) + ml;
                const float4* xp = (const float4*)(x + (size_t)row * 16 + h * 8);
                u0[k] = xp[0]; u1[k] = xp[1];
            }
        }
        #pragma unroll
        for (int k = 0; k < 4; ++k) {
            int t = t0 + k * nwaves;
            if (t < ntiles) {
                bf16x8 xf;
                xf[0] = (__bf16)u0[k].x; xf[1] = (__bf16)u0[k].y;
                xf[2] = (__bf16)u0[k].z; xf[3] = (__bf16)u0[k].w;
                xf[4] = (__bf16)u1[k].x; xf[5] = (__bf16)u1[k].y;
                xf[6] = (__bf16)u1[k].z; xf[7] = (__bf16)u1[k].w;
                tile(t, xf);
            }
        }
    }

    if (STATS) {
        const int wid = tid >> 6;
        #pragma unroll
        for (int i = 0; i < 16; ++i) {
            float s = sums[i], q = sqs[i];
            #pragma unroll
            for (int d = 1; d <= 16; d <<= 1) {
                s += __shfl_xor(s, d);
                q += __shfl_xor(q, d);
            }
            if (ml == 0) {
                int p = (i & 3) + 8 * (i >> 2) + 4 * h;
                s_w[wid][p] = s;
                s_w[wid][32 + p] = q;
            }
        }
        __syncthreads();
        if (tid < 64) {
            float a = s_w[0][tid] + s_w[1][tid] + s_w[2][tid] + s_w[3][tid];
            int L = DEPTH - 1;
            atomicAdd(&stats[L * (NSLOT * 64) + (blockIdx.x & (NSLOT - 1)) * 64 + tid], a);
        }
    }
}

extern "C" void kernel_launch(void* const* d_in, const int* in_sizes, int n_in,
                              void* d_out, int out_size, void* d_ws, size_t ws_size,
                              hipStream_t stream) {
    const float* x   = (const float*)d_in[0];
    const float* W1  = (const float*)d_in[1];
    const float* b1  = (const float*)d_in[2];
    const float* g1  = (const float*)d_in[3];
    const float* be1 = (const float*)d_in[4];
    const float* W2  = (const float*)d_in[5];
    const float* b2  = (const float*)d_in[6];
    const float* g2  = (const float*)d_in[7];
    const float* be2 = (const float*)d_in[8];
    const float* W3  = (const float*)d_in[9];
    const float* b3  = (const float*)d_in[10];
    const float* g3  = (const float*)d_in[11];
    const float* be3 = (const float*)d_in[12];
    const float* W4  = (const float*)d_in[13];
    const float* b4  = (const float*)d_in[14];
    float* out = (float*)d_out;
    int N = in_sizes[0] / 16;

    float* stats = (float*)d_ws;

    hipMemsetAsync(stats, 0, 3 * NSLOT * 64 * sizeof(float), stream);

    k_fwd<1><<<NBLK, NTHR, 0, stream>>>(x, W1, b1, g1, be1, W2, b2, g2, be2, W3, b3, g3, be3, W4, b4, stats, out, N);
    k_fwd<2><<<NBLK, NTHR, 0, stream>>>(x, W1, b1, g1, be1, W2, b2, g2, be2, W3, b3, g3, be3, W4, b4, stats, out, N);
    k_fwd<3><<<NBLK, NTHR, 0, stream>>>(x, W1, b1, g1, be1, W2, b2, g2, be2, W3, b3, g3, be3, W4, b4, stats, out, N);
    k_fwd<4><<<NBLK, NTHR, 0, stream>>>(x, W1, b1, g1, be1, W2, b2, g2, be2, W3, b3, g3, be3, W4, b4, stats, out, N);
}

// Round 6
// 314.894 us; speedup vs baseline: 3.6471x; 1.1445x over previous
//
#include <hip/hip_runtime.h>

#define EPS 1e-5f
#define NTHR 256
#define NBLK 1024
#define NSLOT 16

typedef __bf16 bf16x8 __attribute__((ext_vector_type(8)));
typedef float f32x16 __attribute__((ext_vector_type(16)));

// d_ws layout:
//   [0, N*16*2)              bf16 copy of x, tile-major in MFMA B-frag order:
//                            xb[(t*64 + lane)*8 .. +8) = 8 bf16 for (tile t, lane)
//   [N*16*2, +3*NSLOT*64*4)  stats slots: layer L: stats[L*NSLOT*64 + slot*64 + idx]
//                            idx 0..31 = sum(z_L), 32..63 = sum(z_L^2)
//
// Layout algebra (m74/m101-verified 32x32x16 mappings):
//   C/D: col=lane&31 (data row), row p = (reg&3)+8*(reg>>2)+4h, h=lane>>5
//   A:   m=lane&31, k=8h+j ;  B: n=lane&31, k=8h+j
// Acc regs 0..7 / 8..15 feed the next layer's B-frag; next weights use columns
// permuted by phi(K)=(j&3)+8*(j>>2)+4h+16*kh (involution). BN scale a>0 folds
// into next-layer weight columns; shift e folds into the MFMA accumulator init.
//
// R6: MLP fix. R3's counters imply ~5000 cyc wall per 1KiB tile load with all
// pipes idle => loads were SERIALIZED: every prior "batch" had a per-element
// `if (t < ntiles)` guard, putting each load in its own basic block with
// conservative waitcnts (~1 outstanding load/wave => ~0.9-1.2 TB/s served,
// exactly as measured). Fix: exact contiguous work split (rem handled in a
// separate tail loop) so the main loop is straight-line unguarded batches of
// 4 tiles -> loads issue back-to-back. Everything else = proven R0/R2 code:
// 4 kernels, xb staging (R5 showed dropping it costs +35us), NBLK 1024,
// plain __launch_bounds__ (R4: never cap VGPR below need).

template<int DEPTH>
__global__ __launch_bounds__(NTHR) void k_fwd(
    const float* __restrict__ x, __bf16* __restrict__ xb,
    const float* __restrict__ W1, const float* __restrict__ b1,
    const float* __restrict__ g1, const float* __restrict__ be1,
    const float* __restrict__ W2, const float* __restrict__ b2,
    const float* __restrict__ g2, const float* __restrict__ be2,
    const float* __restrict__ W3, const float* __restrict__ b3,
    const float* __restrict__ g3, const float* __restrict__ be3,
    const float* __restrict__ W4, const float* __restrict__ b4,
    float* __restrict__ stats, float* __restrict__ out, int N)
{
    constexpr bool STATS = (DEPTH < 4);
    __shared__ float s_stat[3][64];
    __shared__ float s_a[3][32];
    __shared__ float s_e[3][32];
    __shared__ float s_w[NTHR / 64][64];

    const int tid = threadIdx.x;
    const float invN = 1.0f / (float)N;

    // Phase A: combine slot partials for layers whose stats are known
    if (tid < 64) {
        for (int L = 0; L < DEPTH - 1; ++L) {
            float a = 0.f;
            #pragma unroll
            for (int s = 0; s < NSLOT; ++s) a += stats[L * (NSLOT * 64) + s * 64 + tid];
            s_stat[L][tid] = a;
        }
    }
    __syncthreads();
    // Phase B: derive BN scale a and additive fold e per feature
    if (tid < 32) {
        const float* gs[3]  = {g1, g2, g3};
        const float* bes[3] = {be1, be2, be3};
        const float* bs[3]  = {b1, b2, b3};
        for (int L = 0; L < DEPTH - 1; ++L) {
            float mu = s_stat[L][tid] * invN;
            float v  = s_stat[L][32 + tid] * invN - mu * mu;
            float a  = gs[L][tid] * rsqrtf(v + EPS);
            s_a[L][tid] = a;
            s_e[L][tid] = bs[L][tid] - mu + bes[L][tid] / a;
        }
    }
    __syncthreads();

    // Phase C: per-thread fragments and constants
    const int lane = tid & 63;
    const int h = lane >> 5;
    const int ml = lane & 31;

    bf16x8 w1f;
    {
        const float* p = W1 + ml * 16 + h * 8;
        #pragma unroll
        for (int j = 0; j < 8; ++j) w1f[j] = (__bf16)p[j];
    }
    bf16x8 w2f0 = {}, w2f1 = {}, w3f0 = {}, w3f1 = {};
    if (DEPTH >= 2) {
        #pragma unroll
        for (int kh = 0; kh < 2; ++kh)
            #pragma unroll
            for (int j = 0; j < 8; ++j) {
                int pk = (j & 3) + 8 * (j >> 2) + 4 * h + 16 * kh;
                float v = W2[ml * 32 + pk] * s_a[0][pk];
                if (kh == 0) w2f0[j] = (__bf16)v; else w2f1[j] = (__bf16)v;
            }
    }
    if (DEPTH >= 3) {
        #pragma unroll
        for (int kh = 0; kh < 2; ++kh)
            #pragma unroll
            for (int j = 0; j < 8; ++j) {
                int pk = (j & 3) + 8 * (j >> 2) + 4 * h + 16 * kh;
                float v = W3[ml * 32 + pk] * s_a[1][pk];
                if (kh == 0) w3f0[j] = (__bf16)v; else w3f1[j] = (__bf16)v;
            }
    }

    f32x16 c1, c2 = {}, c3 = {};
    float w4c[16];
    #pragma unroll
    for (int i = 0; i < 16; ++i) {
        int p = (i & 3) + 8 * (i >> 2) + 4 * h;
        c1[i] = (DEPTH == 1) ? b1[p] : s_e[0][p];
        if (DEPTH >= 2) c2[i] = (DEPTH == 2) ? b2[p] : s_e[1][p];
        if (DEPTH >= 3) c3[i] = (DEPTH == 3) ? b3[p] : s_e[2][p];
        if (DEPTH == 4) w4c[i] = W4[p] * s_a[2][p]; else w4c[i] = 0.f;
    }
    const float b4v = (DEPTH == 4) ? b4[0] : 0.f;

    // exact contiguous split: wave owns tiles [t0, t0+cnt)
    const int ntiles = N >> 5;
    const int nwaves = NBLK * (NTHR / 64);
    const int gwave  = blockIdx.x * (NTHR / 64) + (tid >> 6);
    const int tpw    = ntiles / nwaves;
    const int rem    = ntiles - tpw * nwaves;
    const int t0     = gwave * tpw + (gwave < rem ? gwave : rem);
    const int cnt    = tpw + (gwave < rem ? 1 : 0);

    float sums[16], sqs[16];
    #pragma unroll
    for (int i = 0; i < 16; ++i) { sums[i] = 0.f; sqs[i] = 0.f; }

    auto tile = [&](int t, bf16x8 xf) {
        f32x16 a1 = __builtin_amdgcn_mfma_f32_32x32x16_bf16(w1f, xf, c1, 0, 0, 0);
        if (DEPTH == 1) {
            #pragma unroll
            for (int i = 0; i < 16; ++i) { sums[i] += a1[i]; sqs[i] = fmaf(a1[i], a1[i], sqs[i]); }
            return;
        }
        bf16x8 qa, qb;
        #pragma unroll
        for (int j = 0; j < 8; ++j) {
            qa[j] = (__bf16)fmaxf(a1[j], 0.f);
            qb[j] = (__bf16)fmaxf(a1[8 + j], 0.f);
        }
        f32x16 a2 = __builtin_amdgcn_mfma_f32_32x32x16_bf16(w2f0, qa, c2, 0, 0, 0);
        a2 = __builtin_amdgcn_mfma_f32_32x32x16_bf16(w2f1, qb, a2, 0, 0, 0);
        if (DEPTH == 2) {
            #pragma unroll
            for (int i = 0; i < 16; ++i) { sums[i] += a2[i]; sqs[i] = fmaf(a2[i], a2[i], sqs[i]); }
            return;
        }
        bf16x8 pa, pb;
        #pragma unroll
        for (int j = 0; j < 8; ++j) {
            pa[j] = (__bf16)fmaxf(a2[j], 0.f);
            pb[j] = (__bf16)fmaxf(a2[8 + j], 0.f);
        }
        f32x16 a3 = __builtin_amdgcn_mfma_f32_32x32x16_bf16(w3f0, pa, c3, 0, 0, 0);
        a3 = __builtin_amdgcn_mfma_f32_32x32x16_bf16(w3f1, pb, a3, 0, 0, 0);
        if (DEPTH == 3) {
            #pragma unroll
            for (int i = 0; i < 16; ++i) { sums[i] += a3[i]; sqs[i] = fmaf(a3[i], a3[i], sqs[i]); }
            return;
        }
        float o = 0.f;
        #pragma unroll
        for (int i = 0; i < 16; ++i) o = fmaf(w4c[i], fmaxf(a3[i], 0.f), o);
        o += __shfl_xor(o, 32);
        if (h == 0) out[(t << 5) + ml] = o + b4v;
    };

    auto cvt = [&](float4 a, float4 b) -> bf16x8 {
        bf16x8 xf;
        xf[0] = (__bf16)a.x; xf[1] = (__bf16)a.y; xf[2] = (__bf16)a.z; xf[3] = (__bf16)a.w;
        xf[4] = (__bf16)b.x; xf[5] = (__bf16)b.y; xf[6] = (__bf16)b.z; xf[7] = (__bf16)b.w;
        return xf;
    };

    const int nb4 = cnt & ~3;
    if (DEPTH == 1) {
        // main: unguarded straight-line batches of 4 tiles (8 loads in flight)
        for (int i0 = 0; i0 < nb4; i0 += 4) {
            const float* base = x + (size_t)((t0 + i0) << 5) * 16;
            const float4* p0 = (const float4*)(base + (size_t)(ml)      * 16 + h * 8);
            const float4* p1 = (const float4*)(base + (size_t)(32 + ml) * 16 + h * 8);
            const float4* p2 = (const float4*)(base + (size_t)(64 + ml) * 16 + h * 8);
            const float4* p3 = (const float4*)(base + (size_t)(96 + ml) * 16 + h * 8);
            float4 a0 = p0[0], b0 = p0[1];
            float4 a1 = p1[0], b1_ = p1[1];
            float4 a2 = p2[0], b2_ = p2[1];
            float4 a3 = p3[0], b3_ = p3[1];
            bf16x8 x0 = cvt(a0, b0), x1 = cvt(a1, b1_), x2 = cvt(a2, b2_), x3 = cvt(a3, b3_);
            __bf16* w = xb + ((size_t)(t0 + i0) * 64 + lane) * 8;
            *(bf16x8*)(w)        = x0;
            *(bf16x8*)(w + 512)  = x1;
            *(bf16x8*)(w + 1024) = x2;
            *(bf16x8*)(w + 1536) = x3;
            tile(t0 + i0,     x0);
            tile(t0 + i0 + 1, x1);
            tile(t0 + i0 + 2, x2);
            tile(t0 + i0 + 3, x3);
        }
        for (int i = nb4; i < cnt; ++i) {
            int row = ((t0 + i) << 5) + ml;
            const float4* xp = (const float4*)(x + (size_t)row * 16 + h * 8);
            bf16x8 xf = cvt(xp[0], xp[1]);
            *(bf16x8*)(xb + ((size_t)(t0 + i) * 64 + lane) * 8) = xf;
            tile(t0 + i, xf);
        }
    } else {
        for (int i0 = 0; i0 < nb4; i0 += 4) {
            const __bf16* r = xb + ((size_t)(t0 + i0) * 64 + lane) * 8;
            bf16x8 x0 = *(const bf16x8*)(r);
            bf16x8 x1 = *(const bf16x8*)(r + 512);
            bf16x8 x2 = *(const bf16x8*)(r + 1024);
            bf16x8 x3 = *(const bf16x8*)(r + 1536);
            tile(t0 + i0,     x0);
            tile(t0 + i0 + 1, x1);
            tile(t0 + i0 + 2, x2);
            tile(t0 + i0 + 3, x3);
        }
        for (int i = nb4; i < cnt; ++i) {
            bf16x8 xf = *(const bf16x8*)(xb + ((size_t)(t0 + i) * 64 + lane) * 8);
            tile(t0 + i, xf);
        }
    }

    if (STATS) {
        const int wid = tid >> 6;
        #pragma unroll
        for (int i = 0; i < 16; ++i) {
            float s = sums[i], q = sqs[i];
            #pragma unroll
            for (int d = 1; d <= 16; d <<= 1) {
                s += __shfl_xor(s, d);
                q += __shfl_xor(q, d);
            }
            if (ml == 0) {
                int p = (i & 3) + 8 * (i >> 2) + 4 * h;
                s_w[wid][p] = s;
                s_w[wid][32 + p] = q;
            }
        }
        __syncthreads();
        if (tid < 64) {
            float a = s_w[0][tid] + s_w[1][tid] + s_w[2][tid] + s_w[3][tid];
            int L = DEPTH - 1;
            atomicAdd(&stats[L * (NSLOT * 64) + (blockIdx.x & (NSLOT - 1)) * 64 + tid], a);
        }
    }
}

extern "C" void kernel_launch(void* const* d_in, const int* in_sizes, int n_in,
                              void* d_out, int out_size, void* d_ws, size_t ws_size,
                              hipStream_t stream) {
    const float* x   = (const float*)d_in[0];
    const float* W1  = (const float*)d_in[1];
    const float* b1  = (const float*)d_in[2];
    const float* g1  = (const float*)d_in[3];
    const float* be1 = (const float*)d_in[4];
    const float* W2  = (const float*)d_in[5];
    const float* b2  = (const float*)d_in[6];
    const float* g2  = (const float*)d_in[7];
    const float* be2 = (const float*)d_in[8];
    const float* W3  = (const float*)d_in[9];
    const float* b3  = (const float*)d_in[10];
    const float* g3  = (const float*)d_in[11];
    const float* be3 = (const float*)d_in[12];
    const float* W4  = (const float*)d_in[13];
    const float* b4  = (const float*)d_in[14];
    float* out = (float*)d_out;
    int N = in_sizes[0] / 16;

    __bf16* xb   = (__bf16*)d_ws;
    float* stats = (float*)((char*)d_ws + (size_t)N * 16 * 2);

    hipMemsetAsync(stats, 0, 3 * NSLOT * 64 * sizeof(float), stream);

    k_fwd<1><<<NBLK, NTHR, 0, stream>>>(x, xb, W1, b1, g1, be1, W2, b2, g2, be2, W3, b3, g3, be3, W4, b4, stats, out, N);
    k_fwd<2><<<NBLK, NTHR, 0, stream>>>(x, xb, W1, b1, g1, be1, W2, b2, g2, be2, W3, b3, g3, be3, W4, b4, stats, out, N);
    k_fwd<3><<<NBLK, NTHR, 0, stream>>>(x, xb, W1, b1, g1, be1, W2, b2, g2, be2, W3, b3, g3, be3, W4, b4, stats, out, N);
    k_fwd<4><<<NBLK, NTHR, 0, stream>>>(x, xb, W1, b1, g1, be1, W2, b2, g2, be2, W3, b3, g3, be3, W4, b4, stats, out, N);
}